// Round 3
// baseline (853.094 us; speedup 1.0000x reference)
//
#include <hip/hip_runtime.h>
#include <math.h>

// Problem constants (B,C,H,W fixed by reference)
constexpr int B = 2, C = 256, H = 512, W = 512, P = 32;
constexpr int NR = H / P;      // 16
constexpr int NC = W / P;      // 16
constexpr int NPOS = NR * NC;  // 256
constexpr float EPS = 1e-5f;

// clang ext vector type — required by __builtin_nontemporal_{load,store}
typedef float floatx4 __attribute__((ext_vector_type(4)));

// ---------------------------------------------------------------------------
// K1: 32x32 block-mean pool.  One block per (b, c, br) strip: 32 rows x 512
// cols, coalesced nontemporal float4 loads; writes 16 means into the
// POSITION-MAJOR small tensor xp[b, p, c] so all downstream reads coalesce.
// ---------------------------------------------------------------------------
__global__ void pool_kernel(const float* __restrict__ h_past,
                            float* __restrict__ xp) {
    int bid = blockIdx.x;
    int br = bid & 15;
    int c  = (bid >> 4) & 255;
    int b  = bid >> 12;
    const floatx4* src =
        (const floatx4*)(h_past + (((size_t)(b * C + c)) * H + (size_t)br * P) * W);
    int t    = threadIdx.x;     // 256 threads
    int f4   = t & 127;         // which float4 within a row (row = 128 float4)
    int row0 = t >> 7;          // 0 or 1
    float s = 0.f;
#pragma unroll
    for (int k = 0; k < 16; ++k) {
        floatx4 v = __builtin_nontemporal_load(&src[(row0 + 2 * k) * 128 + f4]);
        s += v.x + v.y + v.z + v.w;
    }
    __shared__ float part[256];
    part[t] = s;
    __syncthreads();
    // bc tile = f4/8 ; 16 partials per bc (8 f4 x 2 row-halves)
    if (t < 16) {
        float acc = 0.f;
#pragma unroll
        for (int j = 0; j < 8; ++j)
            acc += part[t * 8 + j] + part[128 + t * 8 + j];
        // position-major: xp[(b*NPOS + p) * C + c]
        xp[((size_t)(b * NPOS + br * NC + t)) * C + c] = acc * (1.0f / (P * P));
    }
}

// ---------------------------------------------------------------------------
// K2: per-position channel stats (mean + rsqrt(var+eps)).  One block per
// (b,p); coalesced load of the 256-channel vector; wave-shuffle reduction
// (2 barriers instead of 16).
// ---------------------------------------------------------------------------
__global__ void stats_kernel(const float* __restrict__ xp,
                             float* __restrict__ mu_arr,
                             float* __restrict__ rs_arr) {
    int bid = blockIdx.x;            // b*NPOS + p
    int t = threadIdx.x;             // channel
    float v = xp[(size_t)bid * C + t];
    __shared__ float red[8];
    float s = v;
#pragma unroll
    for (int off = 32; off > 0; off >>= 1) s += __shfl_down(s, off, 64);
    int wave = t >> 6, lane = t & 63;
    if (lane == 0) red[wave] = s;
    __syncthreads();
    float mu = (red[0] + red[1] + red[2] + red[3]) * (1.0f / C);
    float d = v - mu;
    float s2 = d * d;
#pragma unroll
    for (int off = 32; off > 0; off >>= 1) s2 += __shfl_down(s2, off, 64);
    if (lane == 0) red[4 + wave] = s2;
    __syncthreads();
    if (t == 0) {
        float var = (red[4] + red[5] + red[6] + red[7]) * (1.0f / C);
        mu_arr[bid] = mu;
        rs_arr[bid] = rsqrtf(var + EPS);
    }
}

// ---------------------------------------------------------------------------
// K3: fused  norm(scale,shift) -> depthwise 3x3 (pad=1) + bias -> exact GELU
//            -> pointwise 1x1 + bias.
// One block per (b,p); thread = channel.  All xp loads are lane-coalesced
// (position-major layout); 9 neighbor positions, normalized on the fly with
// precomputed mu/rs.  Result staged in LDS, then 256-length dot per output
// channel.  Writes z in channel-major [b,c,p] (tiny, L2-absorbed) so the
// upsample kernel's broadcast reads stay cheap.
// ---------------------------------------------------------------------------
__device__ inline float gelu_exact(float x) {
    return 0.5f * x * (1.0f + erff(x * 0.70710678118654752440f));
}

__global__ void fused_kernel(const float* __restrict__ xp,
                             const float* __restrict__ mu_arr,
                             const float* __restrict__ rs_arr,
                             const float* __restrict__ scale,
                             const float* __restrict__ shift,
                             const float* __restrict__ dw_w,
                             const float* __restrict__ dw_b,
                             const float* __restrict__ pw_w,
                             const float* __restrict__ pw_b,
                             float* __restrict__ z) {
    int bid = blockIdx.x;            // b*NPOS + p
    int p = bid & 255;
    int b = bid >> 8;
    int h = p >> 4;
    int w = p & 15;
    int c = threadIdx.x;

    float sc = scale[c];
    float sh = shift[c];
    const float* wt  = dw_w + c * 9;
    const float* xpb = xp + (size_t)b * NPOS * C;
    const float* mub = mu_arr + b * NPOS;
    const float* rsb = rs_arr + b * NPOS;

    float acc = 0.f;
#pragma unroll
    for (int kh = 0; kh < 3; ++kh) {
        int hh = h + kh - 1;
        if (hh < 0 || hh >= NR) continue;
#pragma unroll
        for (int kw = 0; kw < 3; ++kw) {
            int ww = w + kw - 1;
            if (ww < 0 || ww >= NC) continue;
            int q = hh * NC + ww;
            float xv = xpb[(size_t)q * C + c];              // coalesced
            float xn = (xv - mub[q]) * rsb[q] * sc + sh;    // mu/rs broadcast
            acc += xn * wt[kh * 3 + kw];
        }
    }
    float yv = gelu_exact(acc + dw_b[c]);

    __shared__ float ys[256];
    ys[c] = yv;
    __syncthreads();

    const float4* wr = (const float4*)(pw_w + c * C);   // c doubles as out-ch
    const float4* yv4 = (const float4*)ys;
    float acc2 = 0.f;
#pragma unroll 4
    for (int c4 = 0; c4 < 64; ++c4) {
        float4 wv = wr[c4];
        float4 vv = yv4[c4];
        acc2 += wv.x * vv.x + wv.y * vv.y + wv.z * vv.z + wv.w * vv.w;
    }
    z[((size_t)(b * C + c)) * NPOS + p] = acc2 + pw_b[c];
}

// ---------------------------------------------------------------------------
// K4: broadcast-upsample 16x16 -> 512x512.  float4 splat nontemporal writes,
// grid-stride; z reads broadcast within wave and L1/L2-resident.
// ---------------------------------------------------------------------------
__global__ void up_kernel(const float* __restrict__ z,
                          floatx4* __restrict__ out) {
    const int total = B * C * H * (W / 4);  // 33,554,432 float4
    for (int idx = blockIdx.x * 256 + threadIdx.x; idx < total;
         idx += gridDim.x * 256) {
        int w4 = idx & 127;          // W/4 = 128
        int h  = (idx >> 7) & 511;
        int bc = idx >> 16;          // b*C + c  (H*W/4 = 65536 per image)
        float v = z[bc * NPOS + (h >> 5) * NC + (w4 >> 3)];
        floatx4 o = {v, v, v, v};
        __builtin_nontemporal_store(o, &out[idx]);
    }
}

extern "C" void kernel_launch(void* const* d_in, const int* in_sizes, int n_in,
                              void* d_out, int out_size, void* d_ws, size_t ws_size,
                              hipStream_t stream) {
    const float* h_past = (const float*)d_in[0];
    const float* scale  = (const float*)d_in[1];
    const float* shift  = (const float*)d_in[2];
    const float* dw_w   = (const float*)d_in[3];
    const float* dw_b   = (const float*)d_in[4];
    const float* pw_w   = (const float*)d_in[5];
    const float* pw_b   = (const float*)d_in[6];
    float* out = (float*)d_out;

    float* ws = (float*)d_ws;
    const int SMALL = B * C * NPOS;  // 131072 elements
    float* xp = ws;                  // [b, p, c]  position-major
    float* z  = ws + SMALL;          // [b, c, p]  channel-major
    float* mu = ws + 2 * SMALL;      // [b*NPOS]
    float* rs = mu + B * NPOS;       // [b*NPOS]

    pool_kernel<<<B * C * NR, 256, 0, stream>>>(h_past, xp);
    stats_kernel<<<B * NPOS, 256, 0, stream>>>(xp, mu, rs);
    fused_kernel<<<B * NPOS, 256, 0, stream>>>(xp, mu, rs, scale, shift,
                                               dw_w, dw_b, pw_w, pw_b, z);
    up_kernel<<<32768, 256, 0, stream>>>(z, (floatx4*)out);
}